// Round 3
// 82.150 us; speedup vs baseline: 1.0398x; 1.0398x over previous
//
#include <hip/hip_runtime.h>
#include <math.h>

#define N 1024
#define D 512
#define NC 16

static constexpr float THRESH    = 0.5f;
static constexpr float MARGIN    = 0.1f;
static constexpr float SCALE_POS = 0.05f;
static constexpr float SCALE_NEG = 0.002f;
static constexpr float EPS_      = 1e-5f;

typedef __bf16 bf16x8 __attribute__((ext_vector_type(8)));
typedef float  f32x4  __attribute__((ext_vector_type(4)));

__device__ __forceinline__ bf16x8 cvt8(const float4 a, const float4 b) {
    bf16x8 r;
    r[0] = (__bf16)a.x; r[1] = (__bf16)a.y; r[2] = (__bf16)a.z; r[3] = (__bf16)a.w;
    r[4] = (__bf16)b.x; r[5] = (__bf16)b.y; r[6] = (__bf16)b.z; r[7] = (__bf16)b.w;
    return r;
}

// ---------------------------------------------------------------------------
// Kernel 1: fused fp32->bf16 + MFMA GEMM, 32x32 tiles / 1024 blocks.
// R1 lesson: cooperative launch wedges the GPU under this harness (container
// failed; R2's identical-structure plain launch was most likely a victim of
// the same wedged node). Grid-sync fusion is permanently OFF the table.
// vs the 85.4us baseline: 64x64/256 blocks was 1 block/CU (1 wave/SIMD, zero
// TLP) -> every K-phase exposed full global latency + cvt cost serially.
// 32x32/1024 blocks = 4 blocks/CU (4 waves/SIMD) -> wave-level overlap
// (m114) hides both. Plus reg-staged prefetch of the next K-phase (issued
// right after the barrier, consumed next iteration) for ILP within a block.
// LDS 9.2KB, ~64 VGPR -> co-residency is register/LDS-safe.
// Diagonal pinned to 1.0f (fp32 self-sim excluded by the 1-eps test; bf16
// rounding must not let it sneak back in).
// ---------------------------------------------------------------------------
__global__ __launch_bounds__(256) void gemm32(const float* __restrict__ F,
                                              const int* __restrict__ labels,
                                              float* __restrict__ S,
                                              unsigned* __restrict__ mask) {
    __shared__ __bf16 Asm[32][72];   // +8 pad: row stride 144B -> 2-way max (free, m136)
    __shared__ __bf16 Bsm[32][72];

    const int b   = blockIdx.x;
    const int tid = threadIdx.x;

    // ---- label pack: block b packs mask row b ----
    if (tid == 0) {
        const int4* lp = (const int4*)(labels + b * NC);
        unsigned m = 0;
        #pragma unroll
        for (int q = 0; q < 4; ++q) {
            int4 l4 = lp[q];
            if (l4.x == 1) m |= 1u << (q * 4 + 0);
            if (l4.y == 1) m |= 1u << (q * 4 + 1);
            if (l4.z == 1) m |= 1u << (q * 4 + 2);
            if (l4.w == 1) m |= 1u << (q * 4 + 3);
        }
        mask[b] = m;
    }

    const int by = b >> 5, bx = b & 31;
    const int row0 = by * 32, col0 = bx * 32;

    const int wave = tid >> 6;
    const int lane = tid & 63;

    const int sr = tid >> 3;          // staging row 0..31
    const int sk = (tid & 7) * 8;     // staging k-offset 0..56
    const float* Fa = F + (size_t)(row0 + sr) * D + sk;
    const float* Fb = F + (size_t)(col0 + sr) * D + sk;

    const int qr = (wave >> 1) * 16;  // wave's 16x16 output quadrant
    const int qc = (wave & 1) * 16;
    const int lr = lane & 15;
    const int lk = (lane >> 4) * 8;

    // prologue: load K-phase 0 into regs
    float4 fa0 = *(const float4*)(Fa);
    float4 fa1 = *(const float4*)(Fa + 4);
    float4 fb0 = *(const float4*)(Fb);
    float4 fb1 = *(const float4*)(Fb + 4);

    f32x4 acc = {};
    for (int kp = 0; kp < D; kp += 64) {
        *(bf16x8*)(&Asm[sr][sk]) = cvt8(fa0, fa1);
        *(bf16x8*)(&Bsm[sr][sk]) = cvt8(fb0, fb1);
        __syncthreads();
        if (kp + 64 < D) {            // issue next-phase loads; latency hides under MFMA
            fa0 = *(const float4*)(Fa + kp + 64);
            fa1 = *(const float4*)(Fa + kp + 68);
            fb0 = *(const float4*)(Fb + kp + 64);
            fb1 = *(const float4*)(Fb + kp + 68);
        }
        #pragma unroll
        for (int kk = 0; kk < 64; kk += 32) {
            bf16x8 av = *(const bf16x8*)(&Asm[qr + lr][kk + lk]);
            bf16x8 bv = *(const bf16x8*)(&Bsm[qc + lr][kk + lk]);
            acc = __builtin_amdgcn_mfma_f32_16x16x32_bf16(av, bv, acc, 0, 0, 0);
        }
        __syncthreads();
    }

    // C/D layout: col = lane&15, row = (lane>>4)*4 + reg  [m89-verified]
    const int r0 = row0 + qr + (lane >> 4) * 4;
    const int c0 = col0 + qc + lr;
    #pragma unroll
    for (int r = 0; r < 4; ++r) {
        const int rr = r0 + r;
        S[(size_t)rr * N + c0] = (rr == c0) ? 1.0f : acc[r];
    }
}

// ---------------------------------------------------------------------------
// Kernel 2: per-row MS reduction (proven R7 structure — unchanged).
// Block = row i (1024 blocks). Wave w owns classes 4w..4w+3 over all 1024 j.
// Plain store to own slot; no cross-block atomics/fences.
// ---------------------------------------------------------------------------
__global__ __launch_bounds__(256) void ms_reduce(const float* __restrict__ S,
                                                 const unsigned* __restrict__ mask,
                                                 double* __restrict__ partials) {
    const int i    = blockIdx.x;
    const int tid  = threadIdx.x;
    const int lane = tid & 63;
    const int wave = tid >> 6;
    const int cbase = wave * 4;

    float    s[16];
    unsigned mk[16];
    {
        const float4* Srow = (const float4*)(S + (size_t)i * N);
        const uint4*  Mrow = (const uint4*)mask;
        #pragma unroll
        for (int q = 0; q < 4; ++q) {
            float4 v = Srow[lane * 4 + q];
            uint4  m = Mrow[lane * 4 + q];
            s[q * 4 + 0] = v.x; s[q * 4 + 1] = v.y;
            s[q * 4 + 2] = v.z; s[q * 4 + 3] = v.w;
            mk[q * 4 + 0] = m.x; mk[q * 4 + 1] = m.y;
            mk[q * 4 + 2] = m.z; mk[q * 4 + 3] = m.w;
        }
    }

    // ---- pass 1: per-class min_pos / max_neg ----
    float mn[4] = {INFINITY, INFINITY, INFINITY, INFINITY};
    float mx[4] = {-INFINITY, -INFINITY, -INFINITY, -INFINITY};
    #pragma unroll
    for (int u = 0; u < 16; ++u) {
        const float sv = s[u];
        const bool ok1 = sv < 1.0f - EPS_;
        #pragma unroll
        for (int cl = 0; cl < 4; ++cl) {
            const bool pos = (mk[u] >> (cbase + cl)) & 1u;
            mn[cl] = fminf(mn[cl], (pos && ok1) ? sv : INFINITY);
            mx[cl] = fmaxf(mx[cl], pos ? -INFINITY : sv);
        }
    }
    #pragma unroll
    for (int off = 32; off; off >>= 1) {
        #pragma unroll
        for (int cl = 0; cl < 4; ++cl) {
            mn[cl] = fminf(mn[cl], __shfl_xor(mn[cl], off, 64));
            mx[cl] = fmaxf(mx[cl], __shfl_xor(mx[cl], off, 64));
        }
    }
    float mpe[4], mxn[4];
    #pragma unroll
    for (int cl = 0; cl < 4; ++cl) {
        mpe[cl] = (mn[cl] < INFINITY) ? mn[cl] : -INFINITY;
        mxn[cl] = mx[cl];
    }

    // ---- pass 2: selected exp sums ----
    float ps[4] = {}, ns[4] = {};
    #pragma unroll
    for (int u = 0; u < 16; ++u) {
        const float sv = s[u];
        const float ep = __expf(-SCALE_POS * (sv - THRESH));
        const float en = __expf( SCALE_NEG * (sv - THRESH));
        const bool ok1 = sv < 1.0f - EPS_;
        const float sm = sv - MARGIN;
        const float sp = sv + MARGIN;
        #pragma unroll
        for (int cl = 0; cl < 4; ++cl) {
            const bool pos  = (mk[u] >> (cbase + cl)) & 1u;
            const bool psel = pos && ok1 && (sm < mxn[cl]);
            const bool nsel = (!pos) && (sp > mpe[cl]);
            ps[cl] += psel ? ep : 0.0f;
            ns[cl] += nsel ? en : 0.0f;
        }
    }
    #pragma unroll
    for (int off = 32; off; off >>= 1) {
        #pragma unroll
        for (int cl = 0; cl < 4; ++cl) {
            ps[cl] += __shfl_xor(ps[cl], off, 64);
            ns[cl] += __shfl_xor(ns[cl], off, 64);
        }
    }

    // ---- per-wave loss, block combine in LDS, ONE plain store per block ----
    __shared__ double part[4];
    if (lane == 0) {
        const unsigned am = mask[i];
        double lc = 0.0;
        #pragma unroll
        for (int cl = 0; cl < 4; ++cl) {
            const bool anchor = (am >> (cbase + cl)) & 1u;
            if (anchor && ps[cl] > 0.0f && ns[cl] > 0.0f) {
                lc += (double)(log1pf(ps[cl]) * (1.0f / SCALE_POS))
                    + (double)(log1pf(ns[cl]) * (1.0f / SCALE_NEG));
            }
        }
        part[wave] = lc;
    }
    __syncthreads();
    if (tid == 0) {
        partials[i] = part[0] + part[1] + part[2] + part[3];
    }
}

// ---------------------------------------------------------------------------
// Kernel 3: single-block finalize — sum 1024 partials + anchor count
// ---------------------------------------------------------------------------
__global__ __launch_bounds__(256) void finalize(const double* __restrict__ partials,
                                                const unsigned* __restrict__ mask,
                                                float* __restrict__ out) {
    const int tid  = threadIdx.x;
    const int lane = tid & 63;
    const int wave = tid >> 6;

    double s = 0.0;
    int cnt = 0;
    #pragma unroll
    for (int q = 0; q < 4; ++q) {
        s   += partials[tid * 4 + q];
        cnt += __popc(mask[tid * 4 + q]);
    }
    #pragma unroll
    for (int off = 32; off; off >>= 1) {
        s   += __shfl_xor(s, off, 64);
        cnt += __shfl_xor(cnt, off, 64);
    }
    __shared__ double sred[4];
    __shared__ int    cred[4];
    if (lane == 0) { sred[wave] = s; cred[wave] = cnt; }
    __syncthreads();
    if (tid == 0) {
        const double L = sred[0] + sred[1] + sred[2] + sred[3];
        const int    T = cred[0] + cred[1] + cred[2] + cred[3];
        out[0] = (T > 0) ? (float)(L / (double)T) : 0.0f;
    }
}

// ---------------------------------------------------------------------------
extern "C" void kernel_launch(void* const* d_in, const int* in_sizes, int n_in,
                              void* d_out, int out_size, void* d_ws, size_t ws_size,
                              hipStream_t stream) {
    (void)in_sizes; (void)n_in; (void)out_size; (void)ws_size;
    const float* feats  = (const float*)d_in[0];
    const int*   labels = (const int*)d_in[1];
    float*       out    = (float*)d_out;

    // ws layout: [0,4MB) sim | +4KB mask | 1024 doubles partials
    char* ws = (char*)d_ws;
    float*    sim      = (float*)ws;
    unsigned* mask     = (unsigned*)(ws + (size_t)N * N * 4);
    double*   partials = (double*)(ws + (size_t)N * N * 4 + 4096);

    gemm32<<<N, 256, 0, stream>>>(feats, labels, sim, mask);
    ms_reduce<<<N, 256, 0, stream>>>(sim, mask, partials);
    finalize<<<1, 256, 0, stream>>>(partials, mask, out);
}